// Round 10
// baseline (281.471 us; speedup 1.0000x reference)
//
#include <hip/hip_runtime.h>
#include <math.h>

#define NN 512     // N_NODES
#define SD 32      // STATE_DIM == MESSAGE_DIM
#define HM 64      // H_MSG
#define NB 256     // blocks
#define NGRP 16    // barrier tree groups

typedef _Float16 f16x8 __attribute__((ext_vector_type(8)));
typedef float floatx4 __attribute__((ext_vector_type(4)));
typedef unsigned uintx4 __attribute__((ext_vector_type(4)));

// ---- dynamic LDS layout (bytes) ----
#define OFF_HBS   0        // 512 rows x 144 B (packed f16 h-projections) = 73728
#define OFF_M2L   73728    // 16 waves x (16 edges x 144 B packed-f16 m2) = 36864
#define OFF_MSUM  110592   // 16x32 f32 = 2048
#define OFF_HJP   112640   // 2x64 f32
#define OFF_H     113152   // 2x32 f32
#define OFF_MSG   113408   // 2x32 f32
#define OFF_GI    113664   // 2x96 f32
#define OFF_GH    114432   // 2x96 f32
#define LDS_TOTAL 115200

struct KParams {
    const float *J, *b, *mpW1, *mpb1, *mpW2, *mpb2, *mpW3, *mpb3;
    const float *Wih, *Whh, *bih, *bhh;
    const float *rW1, *rb1, *rW2, *rb2, *rW3, *rb3;
    float *out;
    unsigned *hb0, *hb1;   // hip double buffers, packed f16 pairs (512*32 u32)
    unsigned *bar;         // tree barrier state
};

__device__ __forceinline__ float sigmoidf_(float x) {
    return 1.0f / (1.0f + __expf(-x));
}

// ---- packed f16 ops as raw VOP3P (ROCm header-independent) ----------------
__device__ __forceinline__ unsigned pkrtz(float a, float b) {
    unsigned r;
    asm("v_cvt_pkrtz_f16_f32 %0, %1, %2" : "=v"(r) : "v"(a), "v"(b));
    return r;
}
__device__ __forceinline__ unsigned pk_add(unsigned a, unsigned b) {
    unsigned r;
    asm("v_pk_add_f16 %0, %1, %2" : "=v"(r) : "v"(a), "v"(b));
    return r;
}
__device__ __forceinline__ unsigned pk_fma(unsigned a, unsigned b, unsigned c) {
    unsigned r;
    asm("v_pk_fma_f16 %0, %1, %2, %3" : "=v"(r) : "v"(a), "v"(b), "v"(c));
    return r;
}
__device__ __forceinline__ unsigned pk_relu(unsigned a) {
    unsigned r, z = 0u;
    asm("v_pk_max_f16 %0, %1, %2" : "=v"(r) : "v"(a), "v"(z));
    return r;
}

// ---- coherence-point primitives (no cache maintenance anywhere) -----------
__device__ __forceinline__ unsigned ld_bypass_u32(const unsigned* p) {
    unsigned r;
    asm volatile("global_load_dword %0, %1, off sc0 sc1\n\ts_waitcnt vmcnt(0)"
                 : "=v"(r) : "v"(p) : "memory");
    return r;
}
__device__ __forceinline__ void issue16(const unsigned* p, uintx4& d) {
    asm volatile("global_load_dwordx4 %0, %1, off sc0 sc1" : "=&v"(d) : "v"(p));
}
__device__ __forceinline__ void waitall4(uintx4& a, uintx4& b, uintx4& c, uintx4& d) {
    asm volatile("s_waitcnt vmcnt(0)"
                 : "+v"(a), "+v"(b), "+v"(c), "+v"(d) :: "memory");
}

// Tree sense barrier (monotonic rounds, 1-based).
__device__ __forceinline__ void xbarrier(unsigned* bar, unsigned round, int bid) {
    __syncthreads();
    if (threadIdx.x == 0) {
        unsigned g = (unsigned)bid >> 4;
        unsigned old = atomicAdd(&bar[g * 16], 1u);
        if (old + 1u == round * NGRP) {
            unsigned r2 = atomicAdd(&bar[256], 1u);
            if (r2 + 1u == round * NGRP) {
                atomicMax(&bar[272], round);
            } else {
                while (ld_bypass_u32(&bar[272]) < round) __builtin_amdgcn_s_sleep(2);
            }
        } else {
            while (ld_bypass_u32(&bar[272]) < round) __builtin_amdgcn_s_sleep(2);
        }
    }
    __syncthreads();
}

// 256 blocks x 1024 threads (16 waves = 4 waves/SIMD for latency hiding).
// Block owns nodes 2*bid, 2*bid+1 (waves 0-7 / 8-15; each wave 4 groups of
// 16 source rows). Swapped-operand MFMA edge MLP (A=weights, B=activations),
// packed f16, per-wave in-order LDS transpose, stage-all-then-sync staging.
__global__ __launch_bounds__(1024) void fused_kernel(KParams p)
{
    extern __shared__ __align__(16) char smem[];
    char* hbS   = smem + OFF_HBS;                  // packed f16 rows, stride 144 B
    float (*msum)[32] = (float(*)[32])(smem + OFF_MSUM);
    float (*hjpS)[64] = (float(*)[64])(smem + OFF_HJP);
    float (*hS)[32]   = (float(*)[32])(smem + OFF_H);
    float (*msgS)[32] = (float(*)[32])(smem + OFF_MSG);
    float (*giS)[96]  = (float(*)[96])(smem + OFF_GI);
    float (*ghS)[96]  = (float(*)[96])(smem + OFF_GH);

    const int tid  = threadIdx.x;
    const int lane = tid & 63;
    const int wave = tid >> 6;       // 0..15
    const int nsel = wave >> 3;      // node select
    const int nw   = wave & 7;       // wave-within-node (0..7)
    const int j    = blockIdx.x * 2 + nsel;
    const int q    = lane >> 4;
    const int c    = lane & 15;

    char* m2Lw = smem + OFF_M2L + wave * 2304;     // per-wave 16 edges x 144 B

    // ---------------- prep: h==0 projections, packed f16 -> LLC -----------
    if (tid < 128) {
        int node = tid >> 6, cc = tid & 63;
        int jj = blockIdx.x * 2 + node;
        const float* wr = p.mpW1 + cc * 67;
        float bj = p.b[jj];
        hjpS[node][cc] = bj * wr[66] + p.mpb1[cc];
        float si = bj * wr[65];
        float sp = __shfl(si, lane ^ 1);
        if (!(lane & 1))
            atomicExch(&p.hb0[jj * 32 + (cc >> 1)], pkrtz(si, sp));
    }

    // ---------------- persistent per-lane preloads ----------------
    unsigned wj2a[4], wj2b[4];
    #pragma unroll
    for (int i = 0; i < 4; ++i) {
        wj2a[i] = pkrtz(p.mpW1[(q * 8 + 2 * i) * 67 + 64],
                        p.mpW1[(q * 8 + 2 * i + 1) * 67 + 64]);
        wj2b[i] = pkrtz(p.mpW1[(q * 8 + 2 * i + 32) * 67 + 64],
                        p.mpW1[(q * 8 + 2 * i + 33) * 67 + 64]);
    }
    floatx4 b2i[4], b3i[2];
    #pragma unroll
    for (int t4 = 0; t4 < 4; ++t4)
        #pragma unroll
        for (int r = 0; r < 4; ++r) b2i[t4][r] = p.mpb2[t4 * 16 + q * 4 + r];
    #pragma unroll
    for (int t2 = 0; t2 < 2; ++t2)
        #pragma unroll
        for (int r = 0; r < 4; ++r) b3i[t2][r] = p.mpb3[t2 * 16 + q * 4 + r];

    // A-operand weight fragments: Aw2[f][t4][s] = W2[t4*16+c][f*32+q*8+s]
    f16x8 Aw2[2][4], Aw3[2][2];
    #pragma unroll
    for (int f = 0; f < 2; ++f)
        #pragma unroll
        for (int t4 = 0; t4 < 4; ++t4) {
            const float* src = p.mpW2 + (t4 * 16 + c) * 64 + f * 32 + q * 8;
            #pragma unroll
            for (int s = 0; s < 8; ++s) Aw2[f][t4][s] = (_Float16)src[s];
        }
    #pragma unroll
    for (int f = 0; f < 2; ++f)
        #pragma unroll
        for (int t2 = 0; t2 < 2; ++t2) {
            const float* src = p.mpW3 + (t2 * 16 + c) * 64 + f * 32 + q * 8;
            #pragma unroll
            for (int s = 0; s < 8; ++s) Aw3[f][t2][s] = (_Float16)src[s];
        }

    // J values: wave nw handles groups {8k+nw}, k=0..3; lane (k,c) -> row
    const float jA = p.J[((8 * (lane >> 4) + nw) * 16 + (lane & 15)) * NN + j];

    xbarrier(p.bar, 1, blockIdx.x);    // hb0 visible everywhere

    // ---------------- 5 message-passing steps ----------------
    for (int t = 0; t < 5; ++t) {
        const unsigned* hb_read = (t & 1) ? p.hb1 : p.hb0;
        unsigned*       hb_next = (t & 1) ? p.hb0 : p.hb1;

        // per-step hjp packed pairs
        unsigned hjp2a[4], hjp2b[4];
        #pragma unroll
        for (int i = 0; i < 4; ++i) {
            hjp2a[i] = pkrtz(hjpS[nsel][q * 8 + 2 * i], hjpS[nsel][q * 8 + 2 * i + 1]);
            hjp2b[i] = pkrtz(hjpS[nsel][q * 8 + 2 * i + 32], hjpS[nsel][q * 8 + 2 * i + 33]);
        }

        float accf[2][4];
        #pragma unroll
        for (int t2 = 0; t2 < 2; ++t2)
            #pragma unroll
            for (int r = 0; r < 4; ++r) accf[t2][r] = 0.0f;

        // ---- staging: 64 KB hb -> LDS, 64 B/thread, one sync ----
        {
            uintx4 cr[4];
            const unsigned* gp = hb_read + tid * 4;   // 16 B per chunk per thread
            #pragma unroll
            for (int k = 0; k < 4; ++k) issue16(gp + k * 4096, cr[k]);
            waitall4(cr[0], cr[1], cr[2], cr[3]);
            #pragma unroll
            for (int k = 0; k < 4; ++k) {
                int row = k * 128 + (tid >> 3);
                *(uintx4*)(hbS + row * 144 + (tid & 7) * 16) = cr[k];
            }
        }
        __syncthreads();

        // ---- edge phase: 4 groups per wave, swapped MFMA, packed f16 ----
        auto edge_group = [&](int G, float Jv) {
            const char* rb = hbS + (G * 16 + c) * 144;
            uintx4 vlo = *(const uintx4*)(rb + q * 16);
            uintx4 vhi = *(const uintx4*)(rb + 64 + q * 16);
            const unsigned Jp = pkrtz(Jv, Jv);

            uintx4 a0u, a1u;
            #pragma unroll
            for (int i = 0; i < 4; ++i) {
                a0u[i] = pk_relu(pk_fma(Jp, wj2a[i], pk_add(vlo[i], hjp2a[i])));
                a1u[i] = pk_relu(pk_fma(Jp, wj2b[i], pk_add(vhi[i], hjp2b[i])));
            }
            f16x8 B0 = __builtin_bit_cast(f16x8, a0u);
            f16x8 B1 = __builtin_bit_cast(f16x8, a1u);

            // GEMM1 (swapped): c1[t4] lane(q,c): outch=t4*16+q*4+r, edge=c
            floatx4 c1[4];
            #pragma unroll
            for (int t4 = 0; t4 < 4; ++t4) {
                c1[t4] = __builtin_amdgcn_mfma_f32_16x16x32_f16(Aw2[0][t4], B0, b2i[t4], 0, 0, 0);
                c1[t4] = __builtin_amdgcn_mfma_f32_16x16x32_f16(Aw2[1][t4], B1, c1[t4], 0, 0, 0);
            }
            // relu + pack adjacent outch pairs (in-lane) -> 4 ds_write_b64
            #pragma unroll
            for (int t4 = 0; t4 < 4; ++t4) {
                unsigned p0 = pkrtz(fmaxf(c1[t4][0], 0.f), fmaxf(c1[t4][1], 0.f));
                unsigned p1 = pkrtz(fmaxf(c1[t4][2], 0.f), fmaxf(c1[t4][3], 0.f));
                *(uint2*)(m2Lw + c * 144 + t4 * 32 + q * 8) = make_uint2(p0, p1);
            }
            // B2-frags: packed f16 channels, 2 ds_read_b128 (same-wave in-order DS)
            uintx4 rlo = *(const uintx4*)(m2Lw + c * 144 + q * 16);
            uintx4 rhi = *(const uintx4*)(m2Lw + c * 144 + 64 + q * 16);
            f16x8 B2lo = __builtin_bit_cast(f16x8, rlo);
            f16x8 B2hi = __builtin_bit_cast(f16x8, rhi);

            // GEMM2 (swapped): c2[t2] lane(q,c): outch2=t2*16+q*4+r, edge=c
            floatx4 c2[2];
            #pragma unroll
            for (int t2 = 0; t2 < 2; ++t2) {
                c2[t2] = __builtin_amdgcn_mfma_f32_16x16x32_f16(Aw3[0][t2], B2lo, b3i[t2], 0, 0, 0);
                c2[t2] = __builtin_amdgcn_mfma_f32_16x16x32_f16(Aw3[1][t2], B2hi, c2[t2], 0, 0, 0);
            }
            #pragma unroll
            for (int t2 = 0; t2 < 2; ++t2)
                #pragma unroll
                for (int r = 0; r < 4; ++r)
                    accf[t2][r] += fmaxf(c2[t2][r], 0.0f);
        };

        #pragma unroll
        for (int k = 0; k < 4; ++k)
            edge_group(8 * k + nw, __shfl(jA, k * 16 + c));

        // column sums: butterfly over edge lanes c (xor 1,2,4,8 within quad)
        #pragma unroll
        for (int m = 1; m < 16; m <<= 1)
            #pragma unroll
            for (int t2 = 0; t2 < 2; ++t2)
                #pragma unroll
                for (int r = 0; r < 4; ++r)
                    accf[t2][r] += __shfl_xor(accf[t2][r], m);
        if (c == 0) {
            #pragma unroll
            for (int t2 = 0; t2 < 2; ++t2)
                #pragma unroll
                for (int r = 0; r < 4; ++r)
                    msum[wave][t2 * 16 + q * 4 + r] = accf[t2][r];
        }
        __syncthreads();

        // ---- block-local tail ----
        if (tid < 64) {
            int node = tid >> 5, d = tid & 31;
            float s = 0.0f;
            #pragma unroll
            for (int w = 0; w < 8; ++w) s += msum[node * 8 + w][d];
            msgS[node][d] = s;
        }
        __syncthreads();

        if (tid < 192) {
            int node = tid / 96, r = tid % 96;
            int g = r >> 5, d = r & 31;
            const float* wi = p.Wih + (g * 32 + d) * 64;
            float a  = p.bih[g * 32 + d];
            float bb = p.bhh[g * 32 + d];
            if (t > 0) {
                const float* wh = p.Whh + (g * 32 + d) * 32;
                #pragma unroll
                for (int k = 0; k < 32; ++k) {
                    float hv = hS[node][k];
                    a  = fmaf(hv, wi[k], a);
                    bb = fmaf(hv, wh[k], bb);
                }
            }
            #pragma unroll
            for (int k = 0; k < 32; ++k) a = fmaf(msgS[node][k], wi[32 + k], a);
            giS[node][r] = a; ghS[node][r] = bb;
        }
        __syncthreads();

        if (tid < 64) {
            int node = tid >> 5, d = tid & 31;
            float r  = sigmoidf_(giS[node][d] + ghS[node][d]);
            float z  = sigmoidf_(giS[node][32 + d] + ghS[node][32 + d]);
            float ng = tanhf(giS[node][64 + d] + r * ghS[node][64 + d]);
            float hold = (t > 0) ? hS[node][d] : 0.0f;
            hS[node][d] = (1.0f - z) * ng + z * hold;
        }
        __syncthreads();

        if (t < 4) {
            if (tid < 128) {   // projections for next step -> hjpS + LLC (packed f16)
                int node = tid >> 6, cc = tid & 63;
                int jj = blockIdx.x * 2 + node;
                const float* wr = p.mpW1 + cc * 67;
                float bj = p.b[jj];
                float si = bj * wr[65];
                float sj = bj * wr[66] + p.mpb1[cc];
                #pragma unroll
                for (int d = 0; d < 32; ++d) {
                    float hv = hS[node][d];
                    si = fmaf(hv, wr[d], si);
                    sj = fmaf(hv, wr[32 + d], sj);
                }
                hjpS[node][cc] = sj;
                float sp = __shfl(si, lane ^ 1);
                if (!(lane & 1))
                    atomicExch(&hb_next[jj * 32 + (cc >> 1)], pkrtz(si, sp));
            }
            xbarrier(p.bar, (unsigned)(t + 2), blockIdx.x);
        } else {
            if (wave < 2) {   // readout
                int node = wave;
                int jj = blockIdx.x * 2 + node;
                float y1 = p.rb1[lane];
                #pragma unroll
                for (int k = 0; k < 32; ++k) y1 = fmaf(hS[node][k], p.rW1[lane * 32 + k], y1);
                y1 = fmaxf(y1, 0.0f);
                float y2 = p.rb2[lane];
                #pragma unroll
                for (int k = 0; k < 64; ++k) y2 = fmaf(__shfl(y1, k), p.rW2[lane * 64 + k], y2);
                y2 = fmaxf(y2, 0.0f);
                float y3 = (lane < 2) ? p.rb3[lane] : 0.0f;
                #pragma unroll
                for (int k = 0; k < 64; ++k) {
                    float v = __shfl(y2, k);
                    if (lane < 2) y3 = fmaf(v, p.rW3[lane * 64 + k], y3);
                }
                if (lane < 2) p.out[jj * 2 + lane] = sigmoidf_(y3);
            }
        }
    }
}

// ---------------------------------------------------------------------------
extern "C" void kernel_launch(void* const* d_in, const int* in_sizes, int n_in,
                              void* d_out, int out_size, void* d_ws, size_t ws_size,
                              hipStream_t stream)
{
    float* ws = (float*)d_ws;

    KParams p;
    p.J    = (const float*)d_in[0];
    p.b    = (const float*)d_in[1];
    p.mpW1 = (const float*)d_in[2];
    p.mpb1 = (const float*)d_in[3];
    p.mpW2 = (const float*)d_in[4];
    p.mpb2 = (const float*)d_in[5];
    p.mpW3 = (const float*)d_in[6];
    p.mpb3 = (const float*)d_in[7];
    p.Wih  = (const float*)d_in[8];
    p.Whh  = (const float*)d_in[9];
    p.bih  = (const float*)d_in[10];
    p.bhh  = (const float*)d_in[11];
    p.rW1  = (const float*)d_in[12];
    p.rb1  = (const float*)d_in[13];
    p.rW2  = (const float*)d_in[14];
    p.rb2  = (const float*)d_in[15];
    p.rW3  = (const float*)d_in[16];
    p.rb3  = (const float*)d_in[17];
    p.out  = (float*)d_out;

    p.hb0  = (unsigned*)ws;            // 512*32 u32 (packed f16 pairs)
    p.hb1  = (unsigned*)(ws + 16384);
    p.bar  = (unsigned*)(ws + 32768);  // tree barrier state

    (void)hipMemsetAsync(p.bar, 0, 4096, stream);

    (void)hipFuncSetAttribute((const void*)fused_kernel,
                              hipFuncAttributeMaxDynamicSharedMemorySize, LDS_TOTAL);
    fused_kernel<<<dim3(NB), dim3(1024), LDS_TOTAL, stream>>>(p);
}